// Round 2
// baseline (3311.581 us; speedup 1.0000x reference)
//
#include <hip/hip_runtime.h>
#include <math.h>

// PBELoss: power-flow residual loss.
// residual_i = Sbus_i - V_i * conj( sum_{e: dst(e)=i} Y_e * V_{src(e)} )
// out = [ mean|res|, mean|Re res|, mean|Im res| ]

#ifndef PBE_NTHREADS
#define PBE_NTHREADS 256
#endif

// ---------------- Kernel 1: per-node prep -----------------------------------
// x = mask ? pred : target  (6 features)
// V[2i]   = x[VM]*cos(x[VA]);  V[2i+1] = x[VM]*sin(x[VA])
// S[2i]   = x[PG]-x[PD];       S[2i+1] = x[QG]-x[QD]
__global__ void pbe_node_prep(const float* __restrict__ pred,
                              const float* __restrict__ target,
                              const int* __restrict__ mask,
                              float* __restrict__ V,
                              float* __restrict__ S,
                              int n) {
    int i = blockIdx.x * blockDim.x + threadIdx.x;
    int stride = gridDim.x * blockDim.x;
    for (; i < n; i += stride) {
        int b = 6 * i;
        float x0 = mask[b + 0] ? pred[b + 0] : target[b + 0]; // Pd
        float x1 = mask[b + 1] ? pred[b + 1] : target[b + 1]; // Qd
        float x2 = mask[b + 2] ? pred[b + 2] : target[b + 2]; // Pg
        float x3 = mask[b + 3] ? pred[b + 3] : target[b + 3]; // Qg
        float x4 = mask[b + 4] ? pred[b + 4] : target[b + 4]; // Vm
        float x5 = mask[b + 5] ? pred[b + 5] : target[b + 5]; // Va
        float sn, cs;
        sincosf(x5, &sn, &cs);
        V[2 * i + 0] = x4 * cs;
        V[2 * i + 1] = x4 * sn;
        S[2 * i + 0] = x2 - x0;
        S[2 * i + 1] = x3 - x1;
    }
}

// ---------------- Kernel 2: edge scatter -------------------------------------
// msg = (G + iB) * V[src];  I[dst] += msg  (atomic)
__global__ void pbe_edge_scatter(const float* __restrict__ edge_attr, // [E,2]
                                 const int* __restrict__ src,
                                 const int* __restrict__ dst,
                                 const float* __restrict__ V,   // [2N] interleaved
                                 float* __restrict__ I,         // [2N] interleaved
                                 int e_total) {
    int i = blockIdx.x * blockDim.x + threadIdx.x;
    int stride = gridDim.x * blockDim.x;
    for (; i < e_total; i += stride) {
        float2 gb = reinterpret_cast<const float2*>(edge_attr)[i];
        int s = src[i];
        int d = dst[i];
        float2 v = reinterpret_cast<const float2*>(V)[s];
        float mr = gb.x * v.x - gb.y * v.y;
        float mi = gb.x * v.y + gb.y * v.x;
        atomicAdd(&I[2 * d + 0], mr);
        atomicAdd(&I[2 * d + 1], mi);
    }
}

// ---------------- Kernel 3: residual + reduction -----------------------------
__global__ void pbe_reduce(const float* __restrict__ V,
                           const float* __restrict__ S,
                           const float* __restrict__ I,
                           float* __restrict__ sums, // [3]
                           int n) {
    float a0 = 0.f, a1 = 0.f, a2 = 0.f;
    int i = blockIdx.x * blockDim.x + threadIdx.x;
    int stride = gridDim.x * blockDim.x;
    for (; i < n; i += stride) {
        float2 v  = reinterpret_cast<const float2*>(V)[i];
        float2 sb = reinterpret_cast<const float2*>(S)[i];
        float2 cc = reinterpret_cast<const float2*>(I)[i];
        // V*conj(I) = (Vr*Ir + Vi*Ii) + i(Vi*Ir - Vr*Ii)
        float rr = sb.x - (v.x * cc.x + v.y * cc.y);
        float ri = sb.y - (v.y * cc.x - v.x * cc.y);
        a0 += sqrtf(rr * rr + ri * ri);
        a1 += fabsf(rr);
        a2 += fabsf(ri);
    }
    // wave (64-lane) reduction
    #pragma unroll
    for (int off = 32; off > 0; off >>= 1) {
        a0 += __shfl_down(a0, off);
        a1 += __shfl_down(a1, off);
        a2 += __shfl_down(a2, off);
    }
    __shared__ float sm[3][PBE_NTHREADS / 64];
    int wid  = threadIdx.x >> 6;
    int lane = threadIdx.x & 63;
    if (lane == 0) { sm[0][wid] = a0; sm[1][wid] = a1; sm[2][wid] = a2; }
    __syncthreads();
    if (threadIdx.x == 0) {
        float t0 = 0.f, t1 = 0.f, t2 = 0.f;
        #pragma unroll
        for (int w = 0; w < PBE_NTHREADS / 64; ++w) {
            t0 += sm[0][w]; t1 += sm[1][w]; t2 += sm[2][w];
        }
        atomicAdd(&sums[0], t0);
        atomicAdd(&sums[1], t1);
        atomicAdd(&sums[2], t2);
    }
}

// ---------------- Kernel 4: finalize -----------------------------------------
__global__ void pbe_finalize(const float* __restrict__ sums,
                             float* __restrict__ out, float inv_n) {
    int t = threadIdx.x;
    if (t < 3) out[t] = sums[t] * inv_n;
}

extern "C" void kernel_launch(void* const* d_in, const int* in_sizes, int n_in,
                              void* d_out, int out_size, void* d_ws, size_t ws_size,
                              hipStream_t stream) {
    const float* pred      = (const float*)d_in[0];
    const float* target    = (const float*)d_in[1];
    const float* edge_attr = (const float*)d_in[2];
    const int*   edge_idx  = (const int*)d_in[3]; // [2, E]
    const int*   mask      = (const int*)d_in[4]; // bool -> int32

    const int n_nodes = in_sizes[0] / 6;
    const int n_edges = in_sizes[2] / 2;
    const int* src = edge_idx;
    const int* dst = edge_idx + n_edges;

    // Workspace layout (floats):
    //   V    : [0,            2N)
    //   S    : [2N,           4N)
    //   I    : [4N,           6N)
    //   sums : [6N,           6N+3)
    float* wsf = (float*)d_ws;
    float* V    = wsf;
    float* S    = wsf + 2 * (size_t)n_nodes;
    float* I    = wsf + 4 * (size_t)n_nodes;
    float* sums = wsf + 6 * (size_t)n_nodes;

    // Zero the accumulators (graph-capture-safe async memsets).
    hipMemsetAsync(I, 0, 2 * (size_t)n_nodes * sizeof(float), stream);
    hipMemsetAsync(sums, 0, 3 * sizeof(float), stream);

    const int T = PBE_NTHREADS;
    int grid_nodes = (n_nodes + T - 1) / T;
    if (grid_nodes > 4096) grid_nodes = 4096;
    int grid_edges = (n_edges + T - 1) / T;
    if (grid_edges > 8192) grid_edges = 8192;

    pbe_node_prep<<<grid_nodes, T, 0, stream>>>(pred, target, mask, V, S, n_nodes);
    pbe_edge_scatter<<<grid_edges, T, 0, stream>>>(edge_attr, src, dst, V, I, n_edges);
    pbe_reduce<<<grid_nodes, T, 0, stream>>>(V, S, I, sums, n_nodes);
    pbe_finalize<<<1, 64, 0, stream>>>(sums, (float*)d_out, 1.0f / (float)n_nodes);
}

// Round 3
// 1594.107 us; speedup vs baseline: 2.0774x; 2.0774x over previous
//
#include <hip/hip_runtime.h>
#include <math.h>

// PBELoss: power-flow residual loss.
// residual_i = Sbus_i - V_i * conj( sum_{e: dst(e)=i} Y_e * V_{src(e)} )
// out = [ mean|res|, mean|Re res|, mean|Im res| ]
//
// Edge accumulation uses ONE 64-bit atomicAdd per edge: (re,im) packed as two
// signed 32-bit fixed-point fields (scale 2^21). 64-bit integer addition keeps
// the pair exact (carries between fields recovered at unpack time).

#ifndef PBE_NTHREADS
#define PBE_NTHREADS 256
#endif

#define PBE_SCALE     2097152.0f        // 2^21
#define PBE_INV_SCALE (1.0f / 2097152.0f)

__device__ __forceinline__ float2 ld_nt_f2(const float2* p) {
    double d = __builtin_nontemporal_load(reinterpret_cast<const double*>(p));
    union { double d; float2 f; } u; u.d = d;
    return u.f;
}
__device__ __forceinline__ int ld_nt_i(const int* p) {
    return __builtin_nontemporal_load(p);
}

// ---------------- Kernel 1: per-node prep -----------------------------------
__global__ void pbe_node_prep(const float* __restrict__ pred,
                              const float* __restrict__ target,
                              const int* __restrict__ mask,
                              float* __restrict__ V,
                              float* __restrict__ S,
                              int n) {
    int i = blockIdx.x * blockDim.x + threadIdx.x;
    int stride = gridDim.x * blockDim.x;
    for (; i < n; i += stride) {
        int b = 6 * i;
        float x0 = mask[b + 0] ? pred[b + 0] : target[b + 0]; // Pd
        float x1 = mask[b + 1] ? pred[b + 1] : target[b + 1]; // Qd
        float x2 = mask[b + 2] ? pred[b + 2] : target[b + 2]; // Pg
        float x3 = mask[b + 3] ? pred[b + 3] : target[b + 3]; // Qg
        float x4 = mask[b + 4] ? pred[b + 4] : target[b + 4]; // Vm
        float x5 = mask[b + 5] ? pred[b + 5] : target[b + 5]; // Va
        float sn, cs;
        sincosf(x5, &sn, &cs);
        V[2 * i + 0] = x4 * cs;
        V[2 * i + 1] = x4 * sn;
        S[2 * i + 0] = x2 - x0;
        S[2 * i + 1] = x3 - x1;
    }
}

// ---------------- Kernel 2: edge scatter -------------------------------------
__device__ __forceinline__ void pbe_edge_one(float2 gb, int s, int d,
                                             const float2* __restrict__ V,
                                             unsigned long long* __restrict__ Iq) {
    float2 v = V[s];
    float mr = gb.x * v.x - gb.y * v.y;
    float mi = gb.x * v.y + gb.y * v.x;
    int qr = __float2int_rn(mr * PBE_SCALE);
    int qi = __float2int_rn(mi * PBE_SCALE);
    unsigned long long pack =
        ((unsigned long long)(unsigned int)qr << 32) +
        (unsigned long long)(long long)qi;           // sign-extended low field
    atomicAdd(&Iq[d], pack);
}

__global__ void __launch_bounds__(PBE_NTHREADS)
pbe_edge_scatter(const float2* __restrict__ edge_attr, // [E]
                 const int* __restrict__ src,
                 const int* __restrict__ dst,
                 const float2* __restrict__ V,          // [N]
                 unsigned long long* __restrict__ Iq,   // [N] packed fixed-point
                 int e_total) {
    int i = blockIdx.x * blockDim.x + threadIdx.x;
    const int stride = gridDim.x * blockDim.x;
    // 4-way unrolled grid-stride loop: batch loads for memory-level parallelism.
    for (; i + 3 * stride < e_total; i += 4 * stride) {
        int ia = i, ib = i + stride, ic = i + 2 * stride, id = i + 3 * stride;
        float2 ga = ld_nt_f2(edge_attr + ia);
        float2 gb = ld_nt_f2(edge_attr + ib);
        float2 gc = ld_nt_f2(edge_attr + ic);
        float2 gd = ld_nt_f2(edge_attr + id);
        int sa = ld_nt_i(src + ia), sb = ld_nt_i(src + ib);
        int sc = ld_nt_i(src + ic), sd = ld_nt_i(src + id);
        int da = ld_nt_i(dst + ia), db = ld_nt_i(dst + ib);
        int dc = ld_nt_i(dst + ic), dd = ld_nt_i(dst + id);
        pbe_edge_one(ga, sa, da, V, Iq);
        pbe_edge_one(gb, sb, db, V, Iq);
        pbe_edge_one(gc, sc, dc, V, Iq);
        pbe_edge_one(gd, sd, dd, V, Iq);
    }
    for (; i < e_total; i += stride) {
        float2 g = ld_nt_f2(edge_attr + i);
        pbe_edge_one(g, ld_nt_i(src + i), ld_nt_i(dst + i), V, Iq);
    }
}

// ---------------- Kernel 3: residual + reduction -----------------------------
__global__ void pbe_reduce(const float* __restrict__ V,
                           const float* __restrict__ S,
                           const unsigned long long* __restrict__ Iq,
                           float* __restrict__ sums, // [3]
                           int n) {
    float a0 = 0.f, a1 = 0.f, a2 = 0.f;
    int i = blockIdx.x * blockDim.x + threadIdx.x;
    int stride = gridDim.x * blockDim.x;
    for (; i < n; i += stride) {
        float2 v  = reinterpret_cast<const float2*>(V)[i];
        float2 sb = reinterpret_cast<const float2*>(S)[i];
        long long q = (long long)Iq[i];
        int lo = (int)(unsigned int)(q & 0xFFFFFFFFll);   // signed im sum
        int hi = (int)((q - (long long)lo) >> 32);        // signed re sum
        float cr = hi * PBE_INV_SCALE;
        float ci = lo * PBE_INV_SCALE;
        // V*conj(I) = (Vr*Ir + Vi*Ii) + i(Vi*Ir - Vr*Ii)
        float rr = sb.x - (v.x * cr + v.y * ci);
        float ri = sb.y - (v.y * cr - v.x * ci);
        a0 += sqrtf(rr * rr + ri * ri);
        a1 += fabsf(rr);
        a2 += fabsf(ri);
    }
    #pragma unroll
    for (int off = 32; off > 0; off >>= 1) {
        a0 += __shfl_down(a0, off);
        a1 += __shfl_down(a1, off);
        a2 += __shfl_down(a2, off);
    }
    __shared__ float sm[3][PBE_NTHREADS / 64];
    int wid  = threadIdx.x >> 6;
    int lane = threadIdx.x & 63;
    if (lane == 0) { sm[0][wid] = a0; sm[1][wid] = a1; sm[2][wid] = a2; }
    __syncthreads();
    if (threadIdx.x == 0) {
        float t0 = 0.f, t1 = 0.f, t2 = 0.f;
        #pragma unroll
        for (int w = 0; w < PBE_NTHREADS / 64; ++w) {
            t0 += sm[0][w]; t1 += sm[1][w]; t2 += sm[2][w];
        }
        atomicAdd(&sums[0], t0);
        atomicAdd(&sums[1], t1);
        atomicAdd(&sums[2], t2);
    }
}

// ---------------- Kernel 4: finalize -----------------------------------------
__global__ void pbe_finalize(const float* __restrict__ sums,
                             float* __restrict__ out, float inv_n) {
    int t = threadIdx.x;
    if (t < 3) out[t] = sums[t] * inv_n;
}

extern "C" void kernel_launch(void* const* d_in, const int* in_sizes, int n_in,
                              void* d_out, int out_size, void* d_ws, size_t ws_size,
                              hipStream_t stream) {
    const float* pred      = (const float*)d_in[0];
    const float* target    = (const float*)d_in[1];
    const float* edge_attr = (const float*)d_in[2];
    const int*   edge_idx  = (const int*)d_in[3]; // [2, E] as int32
    const int*   mask      = (const int*)d_in[4]; // bool -> int32

    const int n_nodes = in_sizes[0] / 6;
    const int n_edges = in_sizes[2] / 2;
    const int* src = edge_idx;
    const int* dst = edge_idx + n_edges;

    // Workspace layout (bytes): V [0,8N) | S [8N,16N) | Iq [16N,24N) | sums
    float* wsf = (float*)d_ws;
    float* V    = wsf;
    float* S    = wsf + 2 * (size_t)n_nodes;
    unsigned long long* Iq = (unsigned long long*)(wsf + 4 * (size_t)n_nodes);
    float* sums = wsf + 6 * (size_t)n_nodes;

    hipMemsetAsync(Iq, 0, (size_t)n_nodes * sizeof(unsigned long long), stream);
    hipMemsetAsync(sums, 0, 3 * sizeof(float), stream);

    const int T = PBE_NTHREADS;
    int grid_nodes = (n_nodes + T - 1) / T;
    if (grid_nodes > 4096) grid_nodes = 4096;
    int grid_edges = (n_edges + T - 1) / T;
    if (grid_edges > 8192) grid_edges = 8192;

    pbe_node_prep<<<grid_nodes, T, 0, stream>>>(pred, target, mask, V, S, n_nodes);
    pbe_edge_scatter<<<grid_edges, T, 0, stream>>>(
        (const float2*)edge_attr, src, dst, (const float2*)V, Iq, n_edges);
    pbe_reduce<<<grid_nodes, T, 0, stream>>>(V, S, Iq, sums, n_nodes);
    pbe_finalize<<<1, 64, 0, stream>>>(sums, (float*)d_out, 1.0f / (float)n_nodes);
}

// Round 4
// 1354.930 us; speedup vs baseline: 2.4441x; 1.1765x over previous
//
#include <hip/hip_runtime.h>
#include <hip/hip_fp16.h>
#include <math.h>

// PBELoss: power-flow residual loss.
// residual_i = Sbus_i - V_i * conj( sum_{e: dst(e)=i} Y_e * V_{src(e)} )
// out = [ mean|res|, mean|Re res|, mean|Im res| ]
//
// Fast path: dst-binned two-phase aggregation (no per-edge global atomics).
// Fallback (small ws): per-edge packed 64-bit fixed-point atomicAdd.

#define PBE_NT 256

#define PBE_SCALE64       2097152.0f        // 2^21
#define PBE_INV_SCALE64   (1.0f / 2097152.0f)
#define PBE_SCALE_LDS     524288.0f         // 2^19
#define PBE_INV_SCALE_LDS (1.0f / 524288.0f)

#define PBE_BSHIFT 12
#define PBE_BSIZE  4096
#define PBE_MAXB   512
#define PBE_TILE   4096
#define PBE_EPT    (PBE_TILE / PBE_NT)

union H2U { __half2 h; unsigned u; };

__device__ __forceinline__ float2 ld_nt_f2(const float2* p) {
    double d = __builtin_nontemporal_load(reinterpret_cast<const double*>(p));
    union { double d; float2 f; } u; u.d = d;
    return u.f;
}
__device__ __forceinline__ int ld_nt_i(const int* p) {
    return __builtin_nontemporal_load(p);
}

__global__ void pbe_node_prep(const float* __restrict__ pred,
                              const float* __restrict__ target,
                              const int* __restrict__ mask,
                              float* __restrict__ V,
                              float* __restrict__ S,
                              unsigned* __restrict__ Vh,   // may be null
                              int n) {
    int i = blockIdx.x * blockDim.x + threadIdx.x;
    int stride = gridDim.x * blockDim.x;
    for (; i < n; i += stride) {
        int b = 6 * i;
        float x0 = mask[b + 0] ? pred[b + 0] : target[b + 0];
        float x1 = mask[b + 1] ? pred[b + 1] : target[b + 1];
        float x2 = mask[b + 2] ? pred[b + 2] : target[b + 2];
        float x3 = mask[b + 3] ? pred[b + 3] : target[b + 3];
        float x4 = mask[b + 4] ? pred[b + 4] : target[b + 4];
        float x5 = mask[b + 5] ? pred[b + 5] : target[b + 5];
        float sn, cs;
        sincosf(x5, &sn, &cs);
        float vr = x4 * cs, vi = x4 * sn;
        V[2 * i + 0] = vr;
        V[2 * i + 1] = vi;
        S[2 * i + 0] = x2 - x0;
        S[2 * i + 1] = x3 - x1;
        if (Vh) { H2U u; u.h = __floats2half2_rn(vr, vi); Vh[i] = u.u; }
    }
}

__global__ void pbe_hist(const int* __restrict__ dst,
                         unsigned* __restrict__ hist_g, int e_total) {
    __shared__ unsigned h[PBE_MAXB];
    for (int b = threadIdx.x; b < PBE_MAXB; b += blockDim.x) h[b] = 0;
    __syncthreads();
    int i = blockIdx.x * blockDim.x + threadIdx.x;
    int stride = gridDim.x * blockDim.x;
    for (; i < e_total; i += stride)
        atomicAdd(&h[((unsigned)ld_nt_i(dst + i)) >> PBE_BSHIFT], 1u);
    __syncthreads();
    for (int b = threadIdx.x; b < PBE_MAXB; b += blockDim.x)
        if (h[b]) atomicAdd(&hist_g[b], h[b]);
}

__global__ void pbe_prefix(const unsigned* __restrict__ hist_g,
                           unsigned* __restrict__ base,
                           unsigned* __restrict__ cursor) {
    __shared__ unsigned tmp[PBE_MAXB];
    int t = threadIdx.x;
    unsigned mine = hist_g[t];
    tmp[t] = mine;
    __syncthreads();
    for (int o = 1; o < PBE_MAXB; o <<= 1) {
        unsigned u = (t >= o) ? tmp[t - o] : 0u;
        __syncthreads();
        tmp[t] += u;
        __syncthreads();
    }
    unsigned excl = tmp[t] - mine;
    base[t] = excl;
    cursor[t] = excl;
}

__global__ void __launch_bounds__(PBE_NT)
pbe_bin(const float2* __restrict__ Y,
        const int* __restrict__ src,
        const int* __restrict__ dst,
        const unsigned* __restrict__ Vh,
        unsigned long long* __restrict__ rec,
        unsigned* __restrict__ cursor, int e_total) {
    __shared__ unsigned hist[PBE_MAXB];
    __shared__ unsigned lcur[PBE_MAXB];
    __shared__ unsigned goff[PBE_MAXB];
    const int tile0 = blockIdx.x * PBE_TILE;
    for (int b = threadIdx.x; b < PBE_MAXB; b += PBE_NT) { hist[b] = 0; lcur[b] = 0; }
    __syncthreads();
    int d[PBE_EPT];
    #pragma unroll
    for (int k = 0; k < PBE_EPT; ++k) {
        int i = tile0 + k * PBE_NT + threadIdx.x;
        d[k] = (i < e_total) ? ld_nt_i(dst + i) : -1;
        if (d[k] >= 0) atomicAdd(&hist[((unsigned)d[k]) >> PBE_BSHIFT], 1u);
    }
    __syncthreads();
    for (int b = threadIdx.x; b < PBE_MAXB; b += PBE_NT)
        if (hist[b]) goff[b] = atomicAdd(&cursor[b], hist[b]);
    __syncthreads();
    #pragma unroll
    for (int k = 0; k < PBE_EPT; ++k) {
        int i = tile0 + k * PBE_NT + threadIdx.x;
        if (d[k] < 0) continue;
        unsigned b = ((unsigned)d[k]) >> PBE_BSHIFT;
        unsigned r = atomicAdd(&lcur[b], 1u);
        float2 y = ld_nt_f2(Y + i);
        int s = ld_nt_i(src + i);
        H2U uv; uv.u = Vh[s];                      // 4B random gather, 8MB table
        float vr = __low2float(uv.h), vi = __high2float(uv.h);
        float mr = y.x * vr - y.y * vi;
        float mi = y.x * vi + y.y * vr;
        H2U um; um.h = __floats2half2_rn(mr, mi);
        unsigned long long packed =
            ((unsigned long long)(unsigned)(d[k] & (PBE_BSIZE - 1)) << 32) | um.u;
        rec[goff[b] + r] = packed;                 // plain write, L2-combined
    }
}

__global__ void __launch_bounds__(512)
pbe_bucket_acc(const unsigned long long* __restrict__ rec,
               const unsigned* __restrict__ base,
               const unsigned* __restrict__ hist_g,
               float* __restrict__ I, int n_nodes) {
    __shared__ int accR[PBE_BSIZE];
    __shared__ int accI[PBE_BSIZE];
    for (int j = threadIdx.x; j < PBE_BSIZE; j += 512) { accR[j] = 0; accI[j] = 0; }
    __syncthreads();
    const int b = blockIdx.x;
    const unsigned lo = base[b], cnt = hist_g[b];
    for (unsigned t = threadIdx.x; t < cnt; t += 512) {
        unsigned long long p = rec[lo + t];
        H2U um; um.u = (unsigned)p;
        unsigned dl = (unsigned)(p >> 32);
        float mr = __low2float(um.h), mi = __high2float(um.h);
        atomicAdd(&accR[dl], __float2int_rn(mr * PBE_SCALE_LDS));
        atomicAdd(&accI[dl], __float2int_rn(mi * PBE_SCALE_LDS));
    }
    __syncthreads();
    const int node0 = b << PBE_BSHIFT;
    for (int j = threadIdx.x; j < PBE_BSIZE; j += 512) {
        int n = node0 + j;
        if (n < n_nodes) {
            I[2 * n + 0] = accR[j] * PBE_INV_SCALE_LDS;
            I[2 * n + 1] = accI[j] * PBE_INV_SCALE_LDS;
        }
    }
}

// ---- fallback path ----
__device__ __forceinline__ void pbe_edge_one(float2 gb, int s, int d,
                                             const float2* __restrict__ V,
                                             unsigned long long* __restrict__ Iq) {
    float2 v = V[s];
    float mr = gb.x * v.x - gb.y * v.y;
    float mi = gb.x * v.y + gb.y * v.x;
    int qr = __float2int_rn(mr * PBE_SCALE64);
    int qi = __float2int_rn(mi * PBE_SCALE64);
    unsigned long long pack =
        ((unsigned long long)(unsigned int)qr << 32) +
        (unsigned long long)(long long)qi;
    atomicAdd(&Iq[d], pack);
}

__global__ void __launch_bounds__(PBE_NT)
pbe_edge_scatter(const float2* __restrict__ edge_attr,
                 const int* __restrict__ src,
                 const int* __restrict__ dst,
                 const float2* __restrict__ V,
                 unsigned long long* __restrict__ Iq,
                 int e_total) {
    int i = blockIdx.x * blockDim.x + threadIdx.x;
    const int stride = gridDim.x * blockDim.x;
    for (; i + 3 * stride < e_total; i += 4 * stride) {
        int ia = i, ib = i + stride, ic = i + 2 * stride, id = i + 3 * stride;
        float2 ga = ld_nt_f2(edge_attr + ia);
        float2 gb = ld_nt_f2(edge_attr + ib);
        float2 gc = ld_nt_f2(edge_attr + ic);
        float2 gd = ld_nt_f2(edge_attr + id);
        int sa = ld_nt_i(src + ia), sb = ld_nt_i(src + ib);
        int sc = ld_nt_i(src + ic), sd = ld_nt_i(src + id);
        int da = ld_nt_i(dst + ia), db = ld_nt_i(dst + ib);
        int dc = ld_nt_i(dst + ic), dd = ld_nt_i(dst + id);
        pbe_edge_one(ga, sa, da, V, Iq);
        pbe_edge_one(gb, sb, db, V, Iq);
        pbe_edge_one(gc, sc, dc, V, Iq);
        pbe_edge_one(gd, sd, dd, V, Iq);
    }
    for (; i < e_total; i += stride) {
        float2 g = ld_nt_f2(edge_attr + i);
        pbe_edge_one(g, ld_nt_i(src + i), ld_nt_i(dst + i), V, Iq);
    }
}

// In-place unpack: element i reads 8B and rewrites the same 8B (same thread).
__global__ void pbe_unpack_iq(unsigned long long* __restrict__ Iq,
                              float* __restrict__ I, int n) {
    int i = blockIdx.x * blockDim.x + threadIdx.x;
    int stride = gridDim.x * blockDim.x;
    for (; i < n; i += stride) {
        long long q = (long long)Iq[i];
        int lo = (int)(unsigned int)(q & 0xFFFFFFFFll);
        int hi = (int)((q - (long long)lo) >> 32);
        float re = hi * PBE_INV_SCALE64;
        float im = lo * PBE_INV_SCALE64;
        I[2 * i + 0] = re;
        I[2 * i + 1] = im;
    }
}

__global__ void pbe_reduce(const float* __restrict__ V,
                           const float* __restrict__ S,
                           const float* __restrict__ I,
                           float* __restrict__ sums, int n) {
    float a0 = 0.f, a1 = 0.f, a2 = 0.f;
    int i = blockIdx.x * blockDim.x + threadIdx.x;
    int stride = gridDim.x * blockDim.x;
    for (; i < n; i += stride) {
        float2 v  = reinterpret_cast<const float2*>(V)[i];
        float2 sb = reinterpret_cast<const float2*>(S)[i];
        float2 cc = reinterpret_cast<const float2*>(I)[i];
        float rr = sb.x - (v.x * cc.x + v.y * cc.y);
        float ri = sb.y - (v.y * cc.x - v.x * cc.y);
        a0 += sqrtf(rr * rr + ri * ri);
        a1 += fabsf(rr);
        a2 += fabsf(ri);
    }
    #pragma unroll
    for (int off = 32; off > 0; off >>= 1) {
        a0 += __shfl_down(a0, off);
        a1 += __shfl_down(a1, off);
        a2 += __shfl_down(a2, off);
    }
    __shared__ float sm[3][PBE_NT / 64];
    int wid  = threadIdx.x >> 6;
    int lane = threadIdx.x & 63;
    if (lane == 0) { sm[0][wid] = a0; sm[1][wid] = a1; sm[2][wid] = a2; }
    __syncthreads();
    if (threadIdx.x == 0) {
        float t0 = 0.f, t1 = 0.f, t2 = 0.f;
        #pragma unroll
        for (int w = 0; w < PBE_NT / 64; ++w) {
            t0 += sm[0][w]; t1 += sm[1][w]; t2 += sm[2][w];
        }
        atomicAdd(&sums[0], t0);
        atomicAdd(&sums[1], t1);
        atomicAdd(&sums[2], t2);
    }
}

__global__ void pbe_finalize(const float* __restrict__ sums,
                             float* __restrict__ out, float inv_n) {
    int t = threadIdx.x;
    if (t < 3) out[t] = sums[t] * inv_n;
}

static inline size_t align256(size_t x) { return (x + 255) & ~(size_t)255; }

extern "C" void kernel_launch(void* const* d_in, const int* in_sizes, int n_in,
                              void* d_out, int out_size, void* d_ws, size_t ws_size,
                              hipStream_t stream) {
    const float* pred      = (const float*)d_in[0];
    const float* target    = (const float*)d_in[1];
    const float* edge_attr = (const float*)d_in[2];
    const int*   edge_idx  = (const int*)d_in[3]; // [2, E] int32
    const int*   mask      = (const int*)d_in[4]; // bool -> int32

    const int n_nodes = in_sizes[0] / 6;
    const int n_edges = in_sizes[2] / 2;
    const int* src = edge_idx;
    const int* dst = edge_idx + n_edges;

    const int NB = (n_nodes + PBE_BSIZE - 1) / PBE_BSIZE;

    char* w = (char*)d_ws;
    size_t oV    = 0;
    size_t oS    = align256(oV + (size_t)2 * n_nodes * 4);
    size_t oI    = align256(oS + (size_t)2 * n_nodes * 4);
    size_t oVh   = align256(oI + (size_t)2 * n_nodes * 4);
    size_t oRec  = align256(oVh + (size_t)n_nodes * 4);
    size_t oHist = align256(oRec + (size_t)n_edges * 8);
    size_t oBase = align256(oHist + PBE_MAXB * 4);
    size_t oCur  = align256(oBase + PBE_MAXB * 4);
    size_t oSums = align256(oCur + PBE_MAXB * 4);
    size_t need  = oSums + 3 * 4;

    float* V     = (float*)(w + oV);
    float* S     = (float*)(w + oS);
    float* I     = (float*)(w + oI);
    unsigned* Vh = (unsigned*)(w + oVh);
    unsigned long long* rec = (unsigned long long*)(w + oRec);
    unsigned* hist_g = (unsigned*)(w + oHist);
    unsigned* base   = (unsigned*)(w + oBase);
    unsigned* cursor = (unsigned*)(w + oCur);
    float* sums  = (float*)(w + oSums);

    const bool fast = (ws_size >= need) && (NB <= PBE_MAXB);

    const int T = PBE_NT;
    int grid_nodes = (n_nodes + T - 1) / T;
    if (grid_nodes > 4096) grid_nodes = 4096;

    if (fast) {
        hipMemsetAsync(hist_g, 0, PBE_MAXB * sizeof(unsigned), stream);
        hipMemsetAsync(sums, 0, 3 * sizeof(float), stream);

        pbe_node_prep<<<grid_nodes, T, 0, stream>>>(pred, target, mask, V, S, Vh, n_nodes);
        pbe_hist<<<1024, T, 0, stream>>>(dst, hist_g, n_edges);
        pbe_prefix<<<1, PBE_MAXB, 0, stream>>>(hist_g, base, cursor);
        int n_tiles = (n_edges + PBE_TILE - 1) / PBE_TILE;
        pbe_bin<<<n_tiles, T, 0, stream>>>((const float2*)edge_attr, src, dst,
                                           Vh, rec, cursor, n_edges);
        pbe_bucket_acc<<<NB, 512, 0, stream>>>(rec, base, hist_g, I, n_nodes);
        pbe_reduce<<<grid_nodes, T, 0, stream>>>(V, S, I, sums, n_nodes);
        pbe_finalize<<<1, 64, 0, stream>>>(sums, (float*)d_out, 1.0f / (float)n_nodes);
    } else {
        unsigned long long* Iq = (unsigned long long*)(w + oI);
        float* sums_fb = sums; // fits: fallback needs < fast-path footprint? use oVh region
        sums_fb = (float*)(w + oVh);
        hipMemsetAsync(Iq, 0, (size_t)n_nodes * 8, stream);
        hipMemsetAsync(sums_fb, 0, 3 * sizeof(float), stream);
        int grid_edges = (n_edges + T - 1) / T;
        if (grid_edges > 8192) grid_edges = 8192;
        pbe_node_prep<<<grid_nodes, T, 0, stream>>>(pred, target, mask, V, S,
                                                    (unsigned*)nullptr, n_nodes);
        pbe_edge_scatter<<<grid_edges, T, 0, stream>>>(
            (const float2*)edge_attr, src, dst, (const float2*)V, Iq, n_edges);
        pbe_unpack_iq<<<grid_nodes, T, 0, stream>>>(Iq, (float*)(w + oI), n_nodes);
        pbe_reduce<<<grid_nodes, T, 0, stream>>>(V, S, (float*)(w + oI), sums_fb, n_nodes);
        pbe_finalize<<<1, 64, 0, stream>>>(sums_fb, (float*)d_out, 1.0f / (float)n_nodes);
    }
}